// Round 8
// baseline (462.349 us; speedup 1.0000x reference)
//
#include <hip/hip_runtime.h>

#define B_  2
#define S_  2048
#define E_  2048
#define H_  16
#define D_  128
#define BS_ (B_*S_)

typedef __bf16 bf16_t;
typedef __bf16 bf16x8 __attribute__((ext_vector_type(8)));
typedef __bf16 bf16x4 __attribute__((ext_vector_type(4)));
typedef float  f32x4  __attribute__((ext_vector_type(4)));

// combined softmax scale: 1/sqrt(128) * log2(e), folded into Q projection
#define QSCALE 0.1275174131003543f

// ---------------- async global->LDS, 16B per lane per call ----------------
__device__ __forceinline__ void gld16(const bf16_t* g, bf16_t* l) {
    __builtin_amdgcn_global_load_lds(
        (const __attribute__((address_space(1))) void*)g,
        (__attribute__((address_space(3))) void*)l,
        16, 0, 0);
}

// ---------------- fused fp32 -> bf16 convert (x, kv, 4 weights) ----------------
// prefix sums: x 8388608 | kv +8388608 | Wq +4194304 | Wk +262144 | Wv +262144
// | Wo +4194304 ; total 25690112 = 1024*25088
__global__ void cvt_all(const float* __restrict__ s0, const float* __restrict__ s1,
                        const float* __restrict__ s2, const float* __restrict__ s3,
                        const float* __restrict__ s4, const float* __restrict__ s5,
                        bf16_t* d0, bf16_t* d1, bf16_t* d2,
                        bf16_t* d3, bf16_t* d4, bf16_t* d5)
{
    long i = ((long)blockIdx.x * blockDim.x + threadIdx.x) * 4;
    const float* s; bf16_t* d;
    if      (i <  8388608) { s = s0; d = d0; }
    else if (i < 16777216) { s = s1; d = d1; i -=  8388608; }
    else if (i < 20971520) { s = s2; d = d2; i -= 16777216; }
    else if (i < 21233664) { s = s3; d = d3; i -= 20971520; }
    else if (i < 21495808) { s = s4; d = d4; i -= 21233664; }
    else                   { s = s5; d = d5; i -= 21495808; }
    float4 v = *(const float4*)(s + i);
    bf16x4 o;
    o[0] = (bf16_t)v.x; o[1] = (bf16_t)v.y; o[2] = (bf16_t)v.z; o[3] = (bf16_t)v.w;
    *(bf16x4*)(d + i) = o;
}

// ========== GEMM core v2: A in registers, B dbuf-LDS, 1 barrier/K-step ==========
// 256x64 block tile, K=2048 fixed, BK=64. 4 waves stacked: wave w owns rows
// m0+w*64 (disjoint -> no duplicate A traffic). A-fragments load global->VGPR
// directly (same lane->element pattern as attention Q-frags, proven); B-tile
// (64 cols x 64 k = 8 KB) is staged by gld16 into a 2-deep LDS ring.
// Every load (A regs for step k+1, B DMA for step k+1) is issued immediately
// after the barrier that opens step k -> a full step in flight before the
// next barrier's vmcnt drain. One __syncthreads per K-step.
template<int EP>   // EP==0: fp32 store (+biasA). EP==1: bf16 store, dual bias.
__device__ __forceinline__ void gemm_core(
    const bf16_t* __restrict__ A, const bf16_t* __restrict__ W,
    const float* __restrict__ biasA, const float* __restrict__ biasB,
    float* __restrict__ Cf, bf16_t* __restrict__ Cb,
    int N, float scale, int m0_blk, int w_n0, int c_n0,
    bf16_t* Bs)
{
    const int tid  = threadIdx.x;
    const int wave = tid >> 6, lane = tid & 63;
    const int lrow = lane & 15, quad = lane >> 4;
    const int r8 = lane >> 3, c8 = (lane & 7) << 3;
    const int m0 = m0_blk + wave * 64;
    const bf16_t* Arow = A + (size_t)(m0 + lrow) * 2048;

    bf16x8 a0[4][2], a1[4][2];
    f32x4 acc[4][4] = {};

    auto loadA = [&](bf16x8 (&ar)[4][2], int k0) {
#pragma unroll
        for (int mt = 0; mt < 4; ++mt)
#pragma unroll
            for (int ks = 0; ks < 2; ++ks)
                ar[mt][ks] = *(const bf16x8*)(Arow + (size_t)mt * 16 * 2048
                                              + k0 + ks * 32 + quad * 8);
    };
    auto stageB = [&](int k0, int buf) {
#pragma unroll
        for (int j = 0; j < 2; ++j) {
            int base = (wave * 2 + j) * 8;     // wave-uniform row base
            gld16(W + (size_t)(w_n0 + base + r8) * 2048 + k0 + c8,
                  &Bs[buf * 4096 + base * 64]);
        }
    };
    auto compute = [&](bf16x8 (&ar)[4][2], int buf) {
        const bf16_t* Bc = Bs + buf * 4096;
#pragma unroll
        for (int ks = 0; ks < 2; ++ks) {
            bf16x8 bfr[4];
#pragma unroll
            for (int nt = 0; nt < 4; ++nt)
                bfr[nt] = *(const bf16x8*)&Bc[(nt * 16 + lrow) * 64 + ks * 32 + quad * 8];
#pragma unroll
            for (int mt = 0; mt < 4; ++mt)
#pragma unroll
                for (int nt = 0; nt < 4; ++nt)
                    acc[mt][nt] = __builtin_amdgcn_mfma_f32_16x16x32_bf16(
                        ar[mt][ks], bfr[nt], acc[mt][nt], 0, 0, 0);
        }
    };

    loadA(a0, 0);
    stageB(0, 0);
    for (int ki = 0; ki < 32; ki += 2) {
        __syncthreads();                                   // drains step-ki loads
        if (ki + 1 < 32) { stageB((ki + 1) << 6, 1); loadA(a1, (ki + 1) << 6); }
        compute(a0, 0);
        __syncthreads();                                   // drains step-(ki+1) loads
        if (ki + 2 < 32) { stageB((ki + 2) << 6, 0); loadA(a0, (ki + 2) << 6); }
        compute(a1, 1);
    }

#pragma unroll
    for (int mt = 0; mt < 4; ++mt) {
#pragma unroll
        for (int nt = 0; nt < 4; ++nt) {
            int nn = nt * 16 + lrow;
            int col = c_n0 + nn;
            float bvv = (biasB && col >= 128) ? biasB[col - 128] : biasA[col];
#pragma unroll
            for (int r = 0; r < 4; ++r) {
                int row = m0 + mt * 16 + quad * 4 + r;
                float v = (acc[mt][nt][r] + bvv) * scale;
                if (EP == 0) Cf[(size_t)row * N + col] = v;
                else         Cb[(size_t)row * N + col] = (bf16_t)v;
            }
        }
    }
}

// ---------------- fused Q + K + V projection ----------------
// grid (36, 16): bx<32 -> Q col-tile (64 cols, scale QSCALE);
// bx>=32 -> KV col-tile of stacked Wkv (rows 0..127 K, 128..255 V), dual bias.
__global__ __launch_bounds__(256, 2) void gemm_qkv(
    const bf16_t* __restrict__ xb, const bf16_t* __restrict__ kvb,
    const bf16_t* __restrict__ Wq, const bf16_t* __restrict__ Wkv,
    const float* __restrict__ bq, const float* __restrict__ bk,
    const float* __restrict__ bv,
    bf16_t* __restrict__ Qb, bf16_t* __restrict__ KVb)
{
    __shared__ __align__(16) bf16_t Bs[2 * 4096];
    const int m0 = blockIdx.y * 256;
    if (blockIdx.x < 32) {
        int n0 = blockIdx.x * 64;
        gemm_core<1>(xb, Wq, bq, nullptr, nullptr, Qb, E_, QSCALE, m0, n0, n0, Bs);
    } else {
        int n0 = (blockIdx.x - 32) * 64;
        gemm_core<1>(kvb, Wkv, bk, bv, nullptr, KVb, 256, 1.0f, m0, n0, n0, Bs);
    }
}

// ---------------- O projection (fp32 out, direct store) ----------------
__global__ __launch_bounds__(256, 2) void gemm_o(
    const bf16_t* __restrict__ A, const bf16_t* __restrict__ W,
    const float* __restrict__ bias, float* __restrict__ Cf)
{
    __shared__ __align__(16) bf16_t Bs[2 * 4096];
    int n0 = blockIdx.x * 64;
    gemm_core<0>(A, W, bias, nullptr, Cf, nullptr, E_, 1.0f,
                 blockIdx.y * 256, n0, n0, Bs);
}

// ---------------- flash-style causal MQA attention v3 ----------------
// LDS-BW fix: 4 waves x 32 Q-rows (was 8 x 16). Each K/V b128 fragment read
// now feeds TWO MFMAs (two 16-row m-tiles) -> LDS read bytes per Q-row halved.
// Same 512-block grid, complementary qb pairing, reg-prefetch of K/V tiles,
// exp2-domain softmax with deferred normalization.
__global__ __launch_bounds__(256, 2) void mqa_attn(
    const bf16_t* __restrict__ Q, const bf16_t* __restrict__ KV,
    bf16_t* __restrict__ O)
{
    __shared__ __align__(16) bf16_t Kt[64][136];
    __shared__ __align__(16) bf16_t Vt[128][72];
    __shared__ __align__(16) bf16_t Pl[4][32][72];

    const int bx = blockIdx.x, h = blockIdx.y, b = blockIdx.z;
    const int qb = b ? bx : (15 - bx);             // complementary pairing
    const int tid = threadIdx.x, wave = tid >> 6, lane = tid & 63;
    const int lrow = lane & 15, quad = lane >> 4;
    const int q0 = qb * 128 + wave * 32;           // this wave's 32 rows

    const bf16_t* kvp = KV + (size_t)(b * S_) * 256;

    // Q fragments: 2 m-tiles x 4 K-steps, in regs
    bf16x8 qf[2][4];
#pragma unroll
    for (int mt = 0; mt < 2; ++mt) {
        const bf16_t* qp = Q + ((size_t)(b * S_ + q0 + mt * 16 + lrow)) * E_
                           + h * D_ + quad * 8;
#pragma unroll
        for (int ks = 0; ks < 4; ++ks) qf[mt][ks] = *(const bf16x8*)(qp + ks * 32);
    }

    f32x4 oacc[2][8] = {};
    float rs[2][4] = {};

    const int ntiles = 2 * qb + 2;
    bf16x8 kreg[4], vreg[4];

    // preload tile 0 (256 threads x 4 chunks cover 16 KB K + 16 KB V)
#pragma unroll
    for (int i = 0; i < 4; ++i) {
        int c = tid + 256 * i;
        kreg[i] = *(const bf16x8*)(kvp + (size_t)(c >> 4) * 256 + ((c & 15) << 3));
        vreg[i] = *(const bf16x8*)(kvp + (size_t)(c & 63) * 256 + 128 + ((c >> 6) << 3));
    }

    for (int kt = 0; kt < ntiles; ++kt) {
        const int k_base = kt * 64;
        __syncthreads();
#pragma unroll
        for (int i = 0; i < 4; ++i) {
            int c = tid + 256 * i;
            *(bf16x8*)&Kt[c >> 4][(c & 15) << 3] = kreg[i];
            int n = c & 63, d0 = (c >> 6) << 3;
#pragma unroll
            for (int j = 0; j < 8; ++j) Vt[d0 + j][n] = vreg[i][j];
        }
        __syncthreads();
        if (kt + 1 < ntiles) {
            const int nb = (kt + 1) * 64;
#pragma unroll
            for (int i = 0; i < 4; ++i) {
                int c = tid + 256 * i;
                kreg[i] = *(const bf16x8*)(kvp + (size_t)(nb + (c >> 4)) * 256 + ((c & 15) << 3));
                vreg[i] = *(const bf16x8*)(kvp + (size_t)(nb + (c & 63)) * 256 + 128 + ((c >> 6) << 3));
            }
        }

        if (k_base <= q0 + 31) {       // wave skips fully-masked tiles
            // S = Q K^T : 32x64 per wave; each Kt read feeds 2 MFMAs
            f32x4 sc[2][4] = {};
#pragma unroll
            for (int ks = 0; ks < 4; ++ks) {
#pragma unroll
                for (int c = 0; c < 4; ++c) {
                    bf16x8 kb = *(const bf16x8*)&Kt[c * 16 + lrow][ks * 32 + quad * 8];
                    sc[0][c] = __builtin_amdgcn_mfma_f32_16x16x32_bf16(qf[0][ks], kb, sc[0][c], 0, 0, 0);
                    sc[1][c] = __builtin_amdgcn_mfma_f32_16x16x32_bf16(qf[1][ks], kb, sc[1][c], 0, 0, 0);
                }
            }
            const bool diag = (k_base + 63 > q0);
#pragma unroll
            for (int mt = 0; mt < 2; ++mt) {
#pragma unroll
                for (int c = 0; c < 4; ++c) {
#pragma unroll
                    for (int r = 0; r < 4; ++r) {
                        float s = sc[mt][c][r];    // log2-domain score
                        if (diag) {
                            int kj = k_base + c * 16 + lrow;
                            int qi = q0 + mt * 16 + quad * 4 + r;
                            if (kj > qi) s = -1e30f;
                        }
                        float p = exp2f(fminf(s, 110.f));
                        rs[mt][r] += p;
                        Pl[wave][mt * 16 + quad * 4 + r][c * 16 + lrow] = (bf16_t)p;
                    }
                }
            }
            // O += P @ V : each Vt read feeds 2 MFMAs
#pragma unroll
            for (int ks = 0; ks < 2; ++ks) {
                bf16x8 ap0 = *(const bf16x8*)&Pl[wave][lrow][ks * 32 + quad * 8];
                bf16x8 ap1 = *(const bf16x8*)&Pl[wave][16 + lrow][ks * 32 + quad * 8];
#pragma unroll
                for (int dt = 0; dt < 8; ++dt) {
                    bf16x8 bv = *(const bf16x8*)&Vt[dt * 16 + lrow][ks * 32 + quad * 8];
                    oacc[0][dt] = __builtin_amdgcn_mfma_f32_16x16x32_bf16(ap0, bv, oacc[0][dt], 0, 0, 0);
                    oacc[1][dt] = __builtin_amdgcn_mfma_f32_16x16x32_bf16(ap1, bv, oacc[1][dt], 0, 0, 0);
                }
            }
        }
    }

    // epilogue: one shuffle-reduction of row sums, normalize, store
#pragma unroll
    for (int mt = 0; mt < 2; ++mt) {
#pragma unroll
        for (int off = 8; off >= 1; off >>= 1)
#pragma unroll
            for (int r = 0; r < 4; ++r) rs[mt][r] += __shfl_xor(rs[mt][r], off, 16);
#pragma unroll
        for (int r = 0; r < 4; ++r) {
            float inv = 1.0f / rs[mt][r];
            int row = q0 + mt * 16 + quad * 4 + r;
#pragma unroll
            for (int dt = 0; dt < 8; ++dt)
                O[((size_t)(b * S_ + row)) * E_ + h * D_ + dt * 16 + lrow] =
                    (bf16_t)(oacc[mt][dt][r] * inv);
        }
    }
}

// ---------------- launch ----------------
extern "C" void kernel_launch(void* const* d_in, const int* in_sizes, int n_in,
                              void* d_out, int out_size, void* d_ws, size_t ws_size,
                              hipStream_t stream)
{
    const float* x   = (const float*)d_in[0];
    const float* kv  = (const float*)d_in[1];
    const float* Wq  = (const float*)d_in[2];
    const float* bq  = (const float*)d_in[3];
    const float* Wk  = (const float*)d_in[4];
    const float* bk  = (const float*)d_in[5];
    const float* Wv  = (const float*)d_in[6];
    const float* bv  = (const float*)d_in[7];
    const float* Wo  = (const float*)d_in[8];
    const float* bo  = (const float*)d_in[9];
    float* out = (float*)d_out;

    bf16_t* p    = (bf16_t*)d_ws;
    bf16_t* xb   = p;  p += (size_t)BS_ * E_;
    bf16_t* kvb  = p;  p += (size_t)BS_ * E_;
    bf16_t* Wqb  = p;  p += (size_t)E_ * E_;
    bf16_t* Wkvb = p;  p += (size_t)2 * D_ * E_;
    bf16_t* Wob  = p;  p += (size_t)E_ * E_;
    bf16_t* Qb   = p;  p += (size_t)BS_ * E_;
    bf16_t* KVb  = p;  p += (size_t)BS_ * 256;
    bf16_t* Ob   = p;  p += (size_t)BS_ * E_;

    cvt_all<<<dim3(25088), dim3(256), 0, stream>>>(
        x, kv, Wq, Wk, Wv, Wo,
        xb, kvb, Wqb, Wkvb, Wkvb + (size_t)D_ * E_, Wob);

    // fused Q + K + V projections (256x64 tiles, A-in-regs, B dbuf)
    gemm_qkv<<<dim3(36, BS_ / 256), 256, 0, stream>>>(
        xb, kvb, Wqb, Wkvb, bq, bk, bv, Qb, KVb);

    // attention (4 waves x 32 rows)
    mqa_attn<<<dim3(S_ / 128, H_, B_), 256, 0, stream>>>(Qb, KVb, Ob);

    // output projection
    gemm_o<<<dim3(E_ / 64, BS_ / 256), 256, 0, stream>>>(Ob, Wob, bo, out);
}